// Round 4
// baseline (249.742 us; speedup 1.0000x reference)
//
#include <hip/hip_runtime.h>
#include <stdint.h>

// PoolingNms: 3 chained pool/unpool passes (k=3,5,6) on 16x1x1080x1920 fp32.
// lcm(3,5,6)=30 -> 30x30 tiles independent; strips of 30x240 keep global
// accesses 64B-aligned (round-1 lesson: anything narrower amplifies WRITE_SIZE).
//
// [Resubmission: round-3 bench died with "container failed twice" (infra
//  acquisition failure; no compile/absmax/counter evidence). Kernel audited
//  for hang classes (divergent barriers, vmcnt counting, load_lds dest rule,
//  LDS aliasing) - no defect found; logic unchanged.]
//
// Round-2 post-mortem: per-strip time was 10.9us vs ~0.5us of issue -> the
// serial per-window scalar-LDS compute (9..36 ds_read_b32 + serial compare
// chain per window, 3 stages deep) was the critical path, not memory.
//
// Round-3 structure: REGISTER-RESIDENT data-parallel stages.
//   pool_unpool(K) == "keep element iff it equals its KxK window max
//   (row-major first occurrence), else 0". Implemented as:
//     horizontal K-max (thread-local) -> tiny LDS exchange of row-maxes ->
//     vertical K-max with first-row tracking -> elementwise compare.
//   Each thread owns (row, 30-col segment): 30 % {3,5,6} == 0, so all column
//   window boundaries are thread-local; v[30] stays in VGPRs across all 3
//   stages. Ties handled exactly (strict-> ascending row scan + seen-flag
//   per-row scan) == jnp.argmax first-occurrence.
// LDS: tile (28.8KB, linear, global_load_lds dest) + bbuf (31.7KB: two
// 30x132 hmax regions ping-ponged 0,1,0; stride 132 floats = 33 words ->
// rows land on distinct banks; also reused flat as the store transpose).
// Pipeline: prefetch strip i+1 via global_load_lds(16B) during compute of i;
// counted s_waitcnt vmcnt(7) at strip switch (prefetch loads are the oldest
// 7-8 VMEM ops; stores keep flying). No vmcnt(0) in the loop.

#define IMG_H 1080
#define IMG_W 1920
#define TILE_H 30
#define TILE_W 240
#define NTHREADS 256
#define V4PR (TILE_W / 4)            // 60 vec4 per row
#define NV4 (TILE_H * V4PR)          // 1800 vec4 per strip

#define NSX (IMG_W / TILE_W)         // 8
#define NSY (IMG_H / TILE_H)         // 36
#define NBI 16
#define NSTRIPS (NSX * NSY * NBI)    // 4608
#define NBLOCKS 512
#define SPB (NSTRIPS / NBLOCKS)      // 9 strips per block

#define HSTRIDE 132                  // hmax row stride: 33 words -> bank-spread
#define HREG (TILE_H * HSTRIDE)      // 3960 floats per region

#define GPTR(p) ((const __attribute__((address_space(1))) void*)(p))
#define LPTR(p) ((__attribute__((address_space(3))) void*)(p))
#define BAR_LGKM() asm volatile("s_waitcnt lgkmcnt(0)\n\ts_barrier" ::: "memory")
#define BAR_VM0()  asm volatile("s_waitcnt vmcnt(0) lgkmcnt(0)\n\ts_barrier" ::: "memory")
#define BAR_VM7()  asm volatile("s_waitcnt vmcnt(7) lgkmcnt(0)\n\ts_barrier" ::: "memory")

// One stage over register-resident row segment v[30].
// hreg: this stage's 30x132 LDS region (regions ping-pong 0,1,0 so no
// barrier is needed between one stage's reads and the next stage's writes).
template <int K>
__device__ __forceinline__ void stage(float (&v)[TILE_H], float* __restrict__ hreg,
                                      int r, int sseg, bool act) {
    constexpr int NH = TILE_H / K;       // windows per 30-col segment
    constexpr int NG = (NH + 3) / 4;     // 16B granules for the exchange
    if (act) {
        // horizontal K-max, thread-local
        float hpad[NG * 4];
#pragma unroll
        for (int q = 0; q < NG * 4; ++q) hpad[q] = 0.0f;
#pragma unroll
        for (int j = 0; j < NH; ++j) {
            float m = v[j * K];
#pragma unroll
            for (int c = 1; c < K; ++c) m = fmaxf(m, v[j * K + c]);
            hpad[j] = m;
        }
        float* hp = hreg + r * HSTRIDE + sseg * 16;  // 16B-aligned, bank-clean
#pragma unroll
        for (int q = 0; q < NG; ++q)
            *reinterpret_cast<float4*>(hp + 4 * q) =
                *reinterpret_cast<const float4*>(&hpad[4 * q]);
    }
    BAR_LGKM();
    if (act) {
        const int g = r / K;             // window row-group
        const int myrr = r - g * K;      // my row within the group
        float best[NH];
        int frow[NH];
#pragma unroll
        for (int j = 0; j < NH; ++j) { best[j] = -1.0f; frow[j] = -1; }
        const float* vb = hreg + (g * K) * HSTRIDE + sseg * 16;
#pragma unroll
        for (int rr = 0; rr < K; ++rr) {     // ascending + strict '>' keeps
            float hr[NG * 4];                // the FIRST row achieving the max
#pragma unroll
            for (int q = 0; q < NG; ++q)
                *reinterpret_cast<float4*>(&hr[4 * q]) =
                    *reinterpret_cast<const float4*>(vb + rr * HSTRIDE + 4 * q);
#pragma unroll
            for (int j = 0; j < NH; ++j)
                if (hr[j] > best[j]) { best[j] = hr[j]; frow[j] = rr; }
        }
        // elementwise: keep only the first (row-major) occurrence of the max
#pragma unroll
        for (int j = 0; j < NH; ++j) {
            const bool rowwin = (frow[j] == myrr);
            bool seen = false;
#pragma unroll
            for (int c = 0; c < K; ++c) {
                const int idx = j * K + c;
                const bool eq = (v[idx] == best[j]);
                if (!(rowwin && eq && !seen)) v[idx] = 0.0f;
                seen = seen || eq;
            }
        }
    }
}

__global__ __launch_bounds__(NTHREADS) void pooling_nms_kernel(
    const float* __restrict__ x, float* __restrict__ out) {
    __shared__ float tile[TILE_H * TILE_W];  // 28.8 KB, linear (load_lds dest)
    __shared__ float bbuf[2 * HREG];         // 31.7 KB, hmax regions + store xpose

    const int t = threadIdx.x;
    const int s0 = blockIdx.x * SPB;
    const bool act = t < TILE_H * 8;         // 240 compute threads
    const int r = t >> 3;                    // row 0..29
    const int sseg = t & 7;                  // 30-col segment 0..7

    // staging (row, vec4-col), advanced by +256 vec4 without divisions
    const int rv = t / V4PR;
    const int cv = t - rv * V4PR;

    auto strip_base = [&](int s) -> size_t {
        const int xs = s % NSX;
        const int rem = s / NSX;
        const int ys = rem % NSY;
        const int z = rem / NSY;
        return (size_t)z * (IMG_H * (size_t)IMG_W) +
               (size_t)(ys * TILE_H) * IMG_W + (size_t)xs * TILE_W;
    };

    auto prefetch = [&](int s) {  // async global -> LDS, linear dest
        const float* src = x + strip_base(s);
        int rr = rv, cc = cv;
        for (int vv = t; vv < NV4; vv += NTHREADS) {
            __builtin_amdgcn_global_load_lds(
                GPTR(src + (size_t)rr * IMG_W + cc * 4),
                LPTR((char*)tile + (size_t)vv * 16), 16, 0, 0);
            rr += 4; cc += 16;
            if (cc >= V4PR) { cc -= V4PR; rr += 1; }
        }
    };

    float v[TILE_H];

    prefetch(s0);
    BAR_VM0();

    for (int i = 0; i < SPB; ++i) {
        // tile holds strip i. Segment load -> registers (15x ds_read_b64).
        if (act) {
            const float* tp = &tile[r * TILE_W + sseg * 30];
#pragma unroll
            for (int k = 0; k < 15; ++k)
                *reinterpret_cast<float2*>(&v[2 * k]) =
                    *reinterpret_cast<const float2*>(&tp[2 * k]);
        }
        BAR_LGKM();                       // tile free for the next prefetch
        if (i + 1 < SPB) prefetch(s0 + i + 1);  // stays in flight

        stage<3>(v, bbuf, r, sseg, act);          // region 0
        stage<5>(v, bbuf + HREG, r, sseg, act);   // region 1
        stage<6>(v, bbuf, r, sseg, act);          // region 0

        BAR_LGKM();                       // stage<6> reads done everywhere
        if (act) {                        // results -> bbuf flat (store xpose)
            float* bp = &bbuf[r * TILE_W + sseg * 30];
#pragma unroll
            for (int k = 0; k < 15; ++k)
                *reinterpret_cast<float2*>(&bp[2 * k]) =
                    *reinterpret_cast<const float2*>(&v[2 * k]);
        }
        BAR_LGKM();                       // results visible

        {   // coalesced float4 store of strip i
            float* dst = out + strip_base(s0 + i);
            int rr = rv, cc = cv;
            for (int vv = t; vv < NV4; vv += NTHREADS) {
                *reinterpret_cast<float4*>(dst + (size_t)rr * IMG_W + cc * 4) =
                    *reinterpret_cast<const float4*>(&bbuf[vv * 4]);
                rr += 4; cc += 16;
                if (cc >= V4PR) { cc -= V4PR; rr += 1; }
            }
        }
        // Counted wait: the 7-8 prefetch loads are the OLDEST VMEM ops, the
        // 7-8 stores just issued are newest. vmcnt(7) -> all loads landed,
        // stores keep flying. (Wave0 has 8+8: waits 9 oldest = loads + 1 store.)
        BAR_VM7();
    }
}

extern "C" void kernel_launch(void* const* d_in, const int* in_sizes, int n_in,
                              void* d_out, int out_size, void* d_ws, size_t ws_size,
                              hipStream_t stream) {
    const float* x = (const float*)d_in[0];
    float* out = (float*)d_out;
    pooling_nms_kernel<<<dim3(NBLOCKS), NTHREADS, 0, stream>>>(x, out);
}